// Round 8
// baseline (204.317 us; speedup 1.0000x reference)
//
#include <hip/hip_runtime.h>
#include <hip/hip_bf16.h>
#include <math.h>

// Problem constants
#define BB 4
#define TT 2048
#define HH 1024      // HID == H == P == 1024
#define PP 1024
#define MT 8192      // BB*TT rows
#define C2 2048      // packed re/im columns
#define NC 64        // scan chunks
#define LCH 32       // chunk length (TT/NC)

typedef __attribute__((ext_vector_type(8))) short  bf16x8;
typedef __attribute__((ext_vector_type(4))) float  f32x4;

__device__ __forceinline__ ushort f2bf(float f) {
    union { float f; unsigned u; } v; v.f = f;
    unsigned r = v.u + 0x7fffu + ((v.u >> 16) & 1u);   // RNE
    return (ushort)(r >> 16);
}
__device__ __forceinline__ float bf2f(ushort h) {
    union { unsigned u; float f; } v; v.u = ((unsigned)h) << 16;
    return v.f;
}

// async global -> LDS, 16B per lane (dest = wave-uniform base + lane*16)
__device__ __forceinline__ void gload16(const ushort* g, ushort* l) {
    __builtin_amdgcn_global_load_lds((const __attribute__((address_space(1))) void*)g,
                                     (__attribute__((address_space(3))) void*)l,
                                     16, 0, 0);
}
__device__ __forceinline__ void barrier_raw() { __builtin_amdgcn_s_barrier(); }
__device__ __forceinline__ void lgk0() { asm volatile("s_waitcnt lgkmcnt(0)" ::: "memory"); }
__device__ __forceinline__ void vm6()  { asm volatile("s_waitcnt vmcnt(6)"   ::: "memory"); }
__device__ __forceinline__ void vm0()  { asm volatile("s_waitcnt vmcnt(0)"   ::: "memory"); }

// ---------------------------------------------------------------------------
// single fused prep kernel: fp32->bf16 converts (hs, Wi|Wg, Wo) + B/C repacks
#define HS4   (MT * HH / 4)          // 2,097,152 float4 items
#define W4    (HH * HH / 4)          // 262,144 float4 items
#define PREP_CONV  (HS4 + 3 * W4)    // 2,883,584
#define PREP_B     (PREP_CONV + PP * HH)   // + 1,048,576 float2 items
#define PREP_TOT   (PREP_B + HH * PP)      // 4,980,736  (= 256 * 19456)

__global__ void prep_all(const float* __restrict__ hs, const float* __restrict__ Wi,
                         const float* __restrict__ Wg, const float* __restrict__ Wo,
                         const float* __restrict__ B_param, const float* __restrict__ C_param,
                         ushort* __restrict__ hsb, ushort* __restrict__ Wigb,
                         ushort* __restrict__ Wob, ushort* __restrict__ Bpkb,
                         ushort* __restrict__ Cpkb) {
    int i = blockIdx.x * 256 + threadIdx.x;
    if (i < PREP_CONV) {           // float4 convert regions
        const float4* s;
        ushort4* d;
        if (i < HS4)              { s = (const float4*)hs + i;  d = (ushort4*)hsb + i; }
        else if (i < HS4 + 2*W4)  { int j = i - HS4;
                                    s = (const float4*)(j < W4 ? Wi : Wg) + (j < W4 ? j : j - W4);
                                    d = (ushort4*)Wigb + j; }
        else                      { int j = i - HS4 - 2*W4;
                                    s = (const float4*)Wo + j; d = (ushort4*)Wob + j; }
        float4 v = *s;
        ushort4 o;
        o.x = f2bf(v.x); o.y = f2bf(v.y); o.z = f2bf(v.z); o.w = f2bf(v.w);
        *d = o;
    } else if (i < PREP_B) {       // B_param (P,H,2) -> Bpk (2P,H)
        int idx = i - PREP_CONV;
        int p = idx >> 10;
        int h = idx & 1023;
        float2 v = ((const float2*)B_param)[idx];
        Bpkb[(size_t)p * HH + h]        = f2bf(v.x);
        Bpkb[(size_t)(p + PP) * HH + h] = f2bf(v.y);
    } else {                       // C_param (H,P,2) -> Cpk (H,2P), im negated
        int idx = i - PREP_B;
        int h = idx >> 10;
        int p = idx & 1023;
        float2 v = ((const float2*)C_param)[idx];
        Cpkb[(size_t)h * C2 + p]      = f2bf(v.x);
        Cpkb[(size_t)h * C2 + PP + p] = f2bf(-v.y);
    }
}

// ---------------------------------------------------------------------------
// Triple-buffered 2-phase-per-K-tile bf16 MFMA NT GEMM.
// BM=128, BN=256, 512 thr = 8 waves (2Mx4N), 64x64 per wave, BK=64.
// LDS = 3 x (16K A + 32K B) = 144 KiB. Tile t+2 staged while tile t computes:
// every vmcnt wait has >=2-phase (~1600cyc) lead over the ~900cyc HBM latency.
// Ledger (verified):
//  RAW: tile t reads buf bt; its loads issued at t-2 (B at Ph1, A at Ph2),
//       awaited by vm6 at (t-1).Ph2-end [leaves exactly tile-(t+1)'s 6 loads].
//  WAR: stage of buf b2=(t+2)%3 at tile t comes 1 full barrier-pair after its
//       last reads at tile t-1 (each wave lgk0's own reads before barrier2).
//  Prologue: stage tiles 0,1 (12 loads); vm6 drains tile0's 6.
//  Tail: t+2>=nT -> no stage, vm0 (loads awaited are needed next tile anyway).
template<int STORE_BF16>
__global__ __launch_bounds__(512, 2) void gemm3b(
    const ushort* __restrict__ A, int lda,
    const ushort* __restrict__ B, int ldb,
    void* __restrict__ Cp, int ldc, int K, int nbx)
{
    constexpr int BM = 128, BN = 256;
    constexpr int TA = BM * 128;          // 16K bytes
    constexpr int TB = BN * 128;          // 32K bytes
    __shared__ __align__(16) char smem[3 * (TA + TB)];   // A: [0,3TA), B: [3TA,..)

    // bijective XCD swizzle (grid divisible by 8)
    const int bid = blockIdx.x;
    const int cpx = gridDim.x >> 3;
    const int wg  = (bid & 7) * cpx + (bid >> 3);
    const int by  = wg / nbx;
    const int bx  = wg - by * nbx;
    const int bm  = by * BM;
    const int bn  = bx * BN;

    const int tid  = threadIdx.x;
    const int wave = tid >> 6;
    const int lane = tid & 63;
    const int wr   = wave >> 2;
    const int wc   = wave & 3;
    const int lr   = lane & 15;
    const int kg   = lane >> 4;

    // staging: linear LDS dest d = u*8192 + wave*1024 + lane*16;
    // content rule lds[d] = element(swz(d)), swz(o) = o ^ (((o>>7)&7)<<4)
    const int e  = (wave << 10) + ((lane << 4) ^ (((lane >> 3) & 7) << 4));
    const int r0 = e >> 7;            // row within 64-row unit
    const int c0 = (e & 127) >> 1;    // col (bf16 elements)

    auto stA = [&](int bi, int u, int kt) {
        gload16(A + (size_t)(bm + u * 64 + r0) * lda + kt * 64 + c0,
                (ushort*)(smem + bi * TA + u * 8192 + (wave << 10)));
    };
    auto stB = [&](int bi, int u, int kt) {
        gload16(B + (size_t)(bn + u * 64 + r0) * ldb + kt * 64 + c0,
                (ushort*)(smem + 3 * TA + bi * TB + u * 8192 + (wave << 10)));
    };

    bf16x8 Af[2][2], Bf[4][2];
    auto ldsA = [&](int bi, int qm) {
#pragma unroll
        for (int f = 0; f < 2; ++f)
#pragma unroll
            for (int kk = 0; kk < 2; ++kk) {
                int row = wr * 64 + qm * 32 + f * 16 + lr;
                int o = row * 128 + kk * 64 + kg * 16;
                o ^= (row & 7) << 4;
                Af[f][kk] = *(const bf16x8*)(smem + bi * TA + o);
            }
    };
    auto ldsB = [&](int bi) {
#pragma unroll
        for (int n = 0; n < 4; ++n)
#pragma unroll
            for (int kk = 0; kk < 2; ++kk) {
                int row = wc * 64 + n * 16 + lr;
                int o = row * 128 + kk * 64 + kg * 16;
                o ^= (row & 7) << 4;
                Bf[n][kk] = *(const bf16x8*)(smem + 3 * TA + bi * TB + o);
            }
    };

    f32x4 acc[4][4];
#pragma unroll
    for (int m = 0; m < 4; ++m)
#pragma unroll
        for (int n = 0; n < 4; ++n)
#pragma unroll
            for (int i = 0; i < 4; ++i) acc[m][n][i] = 0.f;

    // merged cluster: one qm half x all 4 n-frags x 2 kk = 16 MFMA
    auto cl = [&](int qm) {
        __builtin_amdgcn_s_setprio(1);
#pragma unroll
        for (int f = 0; f < 2; ++f)
#pragma unroll
            for (int n = 0; n < 4; ++n)
#pragma unroll
                for (int kk = 0; kk < 2; ++kk)
                    acc[qm * 2 + f][n] =
                        __builtin_amdgcn_mfma_f32_16x16x32_bf16(
                            Af[f][kk], Bf[n][kk], acc[qm * 2 + f][n], 0, 0, 0);
        __builtin_amdgcn_s_setprio(0);
    };

    // prologue: stage tiles 0 and 1; vm6 drains tile0's 6 loads
    stB(0, 0, 0); stB(0, 1, 0); stB(0, 2, 0); stB(0, 3, 0);
    stA(0, 0, 0); stA(0, 1, 0);
    stB(1, 0, 1); stB(1, 1, 1); stB(1, 2, 1); stB(1, 3, 1);
    stA(1, 0, 1); stA(1, 1, 1);
    vm6();
    barrier_raw();

    const int nT = K >> 6;            // K-tiles of 64 (>= 16 here)
    int bt = 0, b1 = 1, b2 = 2;
    for (int t = 0; t < nT; ++t) {
        const bool pf = (t + 2 < nT);
        // Ph1: read A(qm0)+B of current buffer; stage B of tile t+2
        ldsA(bt, 0); ldsB(bt);
        if (pf) { stB(b2, 0, t + 2); stB(b2, 1, t + 2);
                  stB(b2, 2, t + 2); stB(b2, 3, t + 2); }
        barrier_raw();
        cl(0);
        lgk0();
        barrier_raw();
        // Ph2: read A(qm1); stage A of tile t+2; counted wait for tile t+1
        ldsA(bt, 1);
        if (pf) { stA(b2, 0, t + 2); stA(b2, 1, t + 2); }
        barrier_raw();
        cl(1);
        lgk0();
        if (pf) vm6(); else vm0();
        barrier_raw();
        // rotate buffers
        int tmp = bt; bt = b1; b1 = b2; b2 = tmp;
    }

    // epilogue: D row = (lane>>4)*4 + i, col = lane&15 per fragment
#pragma unroll
    for (int mf = 0; mf < 4; ++mf) {
#pragma unroll
        for (int n = 0; n < 4; ++n) {
            int col = bn + wc * 64 + n * 16 + lr;
#pragma unroll
            for (int i = 0; i < 4; ++i) {
                int row = bm + wr * 64 + mf * 16 + kg * 4 + i;
                float v = acc[mf][n][i];
                if (STORE_BF16)
                    ((ushort*)Cp)[(size_t)row * ldc + col] = f2bf(v);
                else
                    ((float*)Cp)[(size_t)row * ldc + col]  = v;
            }
        }
    }
}

// ---------------------------------------------------------------------------
// Scan (fp32 state, bf16 Bu), chunk-parallel: passA -> combine -> passB
__device__ __forceinline__ void linoss_coeffs(const float* A_diag, const float* dt_p,
                                              int p, float& m11, float& m12,
                                              float& m21, float& m22,
                                              float& f1, float& f2) {
    float A  = fmaxf(A_diag[p], 0.f);
    float dt = 1.f / (1.f + expf(-dt_p[p]));
    float S  = 1.f / (1.f + dt * dt * A);
    m11 = S;        m12 = -dt * A * S;
    m21 = dt * S;   m22 = S;
    f1  = dt * S;   f2  = dt * dt * S;
}

__global__ void scan_passA(const ushort* __restrict__ Bu,
                           const float* __restrict__ A_diag,
                           const float* __restrict__ dt_p,
                           float2* __restrict__ sEnd) {
    int c = blockIdx.x * 256 + threadIdx.x;
    int b = blockIdx.y;
    int j = blockIdx.z;
    float m11, m12, m21, m22, f1, f2;
    linoss_coeffs(A_diag, dt_p, c & 1023, m11, m12, m21, m22, f1, f2);
    const ushort* bu = Bu + ((size_t)(b * TT + j * LCH)) * C2 + c;
    float z = 0.f, y = 0.f;
#pragma unroll 8
    for (int i = 0; i < LCH; ++i) {
        float u  = bf2f(bu[(size_t)i * C2]);
        float z1 = m11 * z + m12 * y + f1 * u;
        float y1 = m21 * z + m22 * y + f2 * u;
        z = z1; y = y1;
    }
    sEnd[((size_t)j * BB + b) * C2 + c] = make_float2(z, y);
}

__global__ void scan_combine(const float* __restrict__ A_diag,
                             const float* __restrict__ dt_p,
                             const float2* __restrict__ sEnd,
                             float2* __restrict__ sInit) {
    int idx = blockIdx.x * 256 + threadIdx.x;   // 0..8191
    int c = idx & (C2 - 1);
    int b = idx >> 11;
    float m11, m12, m21, m22, f1, f2;
    linoss_coeffs(A_diag, dt_p, c & 1023, m11, m12, m21, m22, f1, f2);
    float e11 = m11, e12 = m12, e21 = m21, e22 = m22;   // M^32 by 5 squarings
#pragma unroll
    for (int s = 0; s < 5; ++s) {
        float n11 = e11 * e11 + e12 * e21;
        float n12 = e11 * e12 + e12 * e22;
        float n21 = e21 * e11 + e22 * e21;
        float n22 = e21 * e12 + e22 * e22;
        e11 = n11; e12 = n12; e21 = n21; e22 = n22;
    }
    float z = 0.f, y = 0.f;
    for (int j = 0; j < NC; ++j) {
        size_t off = ((size_t)j * BB + b) * C2 + c;
        sInit[off] = make_float2(z, y);
        float2 le = sEnd[off];
        float z1 = e11 * z + e12 * y + le.x;
        float y1 = e21 * z + e22 * y + le.y;
        z = z1; y = y1;
    }
}

__global__ void scan_passB(const ushort* __restrict__ Bu,
                           const float* __restrict__ A_diag,
                           const float* __restrict__ dt_p,
                           const float2* __restrict__ sInit,
                           ushort* __restrict__ YSb) {
    int c = blockIdx.x * 256 + threadIdx.x;
    int b = blockIdx.y;
    int j = blockIdx.z;
    float m11, m12, m21, m22, f1, f2;
    linoss_coeffs(A_diag, dt_p, c & 1023, m11, m12, m21, m22, f1, f2);
    float2 s0 = sInit[((size_t)j * BB + b) * C2 + c];
    float z = s0.x, y = s0.y;
    const ushort* bu = Bu  + ((size_t)(b * TT + j * LCH)) * C2 + c;
    ushort*       ys = YSb + ((size_t)(b * TT + j * LCH)) * C2 + c;
#pragma unroll 8
    for (int i = 0; i < LCH; ++i) {
        float u  = bf2f(bu[(size_t)i * C2]);
        float z1 = m11 * z + m12 * y + f1 * u;
        float y1 = m21 * z + m22 * y + f2 * u;
        z = z1; y = y1;
        ys[(size_t)i * C2] = f2bf(y);
    }
}

// ---------------------------------------------------------------------------
// Fused epilogue: o = O(bf16) + D*x ; rms-normalize ; * nw * swish(g) -> V
__global__ void rmsgate_kernel(const ushort* __restrict__ O,
                               const ushort* __restrict__ XGb,
                               const float* __restrict__ Dv,
                               const float* __restrict__ nw,
                               ushort* __restrict__ V) {
    int m = blockIdx.x;
    int t = threadIdx.x;
    ushort4 o4 = ((const ushort4*)(O + (size_t)m * HH))[t];
    ushort4 x4 = ((const ushort4*)(XGb + (size_t)m * C2))[t];
    float4  d4 = ((const float4*)Dv)[t];
    float of[4];
    of[0] = bf2f(o4.x) + d4.x * bf2f(x4.x);
    of[1] = bf2f(o4.y) + d4.y * bf2f(x4.y);
    of[2] = bf2f(o4.z) + d4.z * bf2f(x4.z);
    of[3] = bf2f(o4.w) + d4.w * bf2f(x4.w);
    float ss = of[0]*of[0] + of[1]*of[1] + of[2]*of[2] + of[3]*of[3];
#pragma unroll
    for (int o = 32; o > 0; o >>= 1) ss += __shfl_down(ss, o);
    __shared__ float wsum[4];
    if ((t & 63) == 0) wsum[t >> 6] = ss;
    __syncthreads();
    float tot = wsum[0] + wsum[1] + wsum[2] + wsum[3];
    float r = rsqrtf(tot * (1.f / (float)HH) + 1e-5f);

    ushort4 g4 = ((const ushort4*)(XGb + (size_t)m * C2 + HH))[t];
    float4  w4 = ((const float4*)nw)[t];
    float g[4] = {bf2f(g4.x), bf2f(g4.y), bf2f(g4.z), bf2f(g4.w)};
    float w[4] = {w4.x, w4.y, w4.z, w4.w};
    ushort4 vout;
    ushort* vo = &vout.x;
#pragma unroll
    for (int i = 0; i < 4; ++i) {
        float sw = g[i] / (1.f + expf(-g[i]));
        vo[i] = f2bf(of[i] * r * w[i] * sw);
    }
    ((ushort4*)(V + (size_t)m * HH))[t] = vout;
}

// ---------------------------------------------------------------------------
extern "C" void kernel_launch(void* const* d_in, const int* in_sizes, int n_in,
                              void* d_out, int out_size, void* d_ws, size_t ws_size,
                              hipStream_t stream) {
    const float* hs      = (const float*)d_in[0];
    const float* Wi      = (const float*)d_in[1];
    const float* Wg      = (const float*)d_in[2];
    const float* Wo      = (const float*)d_in[3];
    const float* A_diag  = (const float*)d_in[4];
    const float* B_param = (const float*)d_in[5];
    const float* C_param = (const float*)d_in[6];
    const float* Dv      = (const float*)d_in[7];
    const float* dtp     = (const float*)d_in[8];
    const float* nw      = (const float*)d_in[9];
    float* out = (float*)d_out;

    char* ws = (char*)d_ws;
    ushort* hsb  = (ushort*)ws;                                   ws += (size_t)MT * HH * 2;   // 16 MB
    ushort* Wigb = (ushort*)ws;                                   ws += (size_t)C2 * HH * 2;   //  4 MB
    ushort* Wob  = (ushort*)ws;                                   ws += (size_t)HH * HH * 2;   //  2 MB
    ushort* Bpkb = (ushort*)ws;                                   ws += (size_t)C2 * HH * 2;   //  4 MB
    ushort* Cpkb = (ushort*)ws;                                   ws += (size_t)HH * C2 * 2;   //  4 MB
    ushort* XGb  = (ushort*)ws;                                   ws += (size_t)MT * C2 * 2;   // 32 MB
    ushort* Bu   = (ushort*)ws;                                   ws += (size_t)MT * C2 * 2;   // 32 MB
    ushort* YSb  = (ushort*)ws;                                   ws += (size_t)MT * C2 * 2;   // 32 MB
    ushort* O    = (ushort*)ws;                                   ws += (size_t)MT * HH * 2;   // 16 MB
    ushort* Vb   = (ushort*)ws;                                   ws += (size_t)MT * HH * 2;   // 16 MB
    float2* sEnd  = (float2*)ws;                                  ws += (size_t)NC * BB * C2 * 8;
    float2* sInit = (float2*)ws;

    dim3 blk(256);

    // single fused prep kernel (converts + repacks)
    prep_all<<<dim3(PREP_TOT / 256), blk, 0, stream>>>(
        hs, Wi, Wg, Wo, B_param, C_param, hsb, Wigb, Wob, Bpkb, Cpkb);

    // XG = hs @ [Wi|Wg]^T   (M=8192, N=2048, K=1024) -> bf16, 512 blocks
    gemm3b<1><<<dim3(512), dim3(512), 0, stream>>>(
        hsb, HH, Wigb, HH, XGb, C2, HH, 8);

    // Bu = x @ Bpk^T        (M=8192, N=2048, K=1024) -> bf16, 512 blocks
    gemm3b<1><<<dim3(512), dim3(512), 0, stream>>>(
        XGb, C2, Bpkb, HH, Bu, C2, HH, 8);

    // chunked linear scan (fp32 state over bf16 Bu), YS emitted as bf16
    scan_passA<<<dim3(C2 / 256, BB, NC), blk, 0, stream>>>(Bu, A_diag, dtp, sEnd);
    scan_combine<<<dim3((BB * C2) / 256), blk, 0, stream>>>(A_diag, dtp, sEnd, sInit);
    scan_passB<<<dim3(C2 / 256, BB, NC), blk, 0, stream>>>(Bu, A_diag, dtp, sInit, YSb);

    // O = YS @ Cpk^T        (M=8192, N=1024, K=2048) -> bf16, 256 blocks
    gemm3b<1><<<dim3(256), dim3(512), 0, stream>>>(
        YSb, C2, Cpkb, C2, O, HH, C2, 4);

    // fused D*x + RMSNorm + swish gate -> V (bf16)
    rmsgate_kernel<<<dim3(MT), blk, 0, stream>>>(O, XGb, Dv, nw, Vb);

    // out = V @ Wo^T        (M=8192, N=1024, K=1024) -> fp32, 256 blocks
    gemm3b<0><<<dim3(256), dim3(512), 0, stream>>>(
        Vb, HH, Wob, HH, out, HH, HH, 4);
}

// Round 9
// 187.894 us; speedup vs baseline: 1.0874x; 1.0874x over previous
//
#include <hip/hip_runtime.h>
#include <hip/hip_bf16.h>
#include <math.h>

// Problem constants
#define BB 4
#define TT 2048
#define HH 1024      // HID == H == P == 1024
#define PP 1024
#define MT 8192      // BB*TT rows
#define C2 2048      // packed re/im columns
#define NC 64        // scan chunks
#define LCH 32       // chunk length (TT/NC)

typedef __attribute__((ext_vector_type(8))) short  bf16x8;
typedef __attribute__((ext_vector_type(4))) float  f32x4;

__device__ __forceinline__ ushort f2bf(float f) {
    union { float f; unsigned u; } v; v.f = f;
    unsigned r = v.u + 0x7fffu + ((v.u >> 16) & 1u);   // RNE
    return (ushort)(r >> 16);
}
__device__ __forceinline__ float bf2f(ushort h) {
    union { unsigned u; float f; } v; v.u = ((unsigned)h) << 16;
    return v.f;
}

// async global -> LDS, 16B per lane (dest = wave-uniform base + lane*16)
__device__ __forceinline__ void gload16(const ushort* g, ushort* l) {
    __builtin_amdgcn_global_load_lds((const __attribute__((address_space(1))) void*)g,
                                     (__attribute__((address_space(3))) void*)l,
                                     16, 0, 0);
}
__device__ __forceinline__ void barrier_raw() { __builtin_amdgcn_s_barrier(); }
__device__ __forceinline__ void lgk0() { asm volatile("s_waitcnt lgkmcnt(0)" ::: "memory"); }
__device__ __forceinline__ void lgk8() { asm volatile("s_waitcnt lgkmcnt(8)" ::: "memory"); }
__device__ __forceinline__ void vm6()  { asm volatile("s_waitcnt vmcnt(6)"   ::: "memory"); }
__device__ __forceinline__ void vm0()  { asm volatile("s_waitcnt vmcnt(0)"   ::: "memory"); }

// ---------------------------------------------------------------------------
// single fused prep kernel: fp32->bf16 converts (hs, Wi|Wg, Wo) + B/C repacks
#define HS4   (MT * HH / 4)          // 2,097,152 float4 items
#define W4    (HH * HH / 4)          // 262,144 float4 items
#define PREP_CONV  (HS4 + 3 * W4)    // 2,883,584
#define PREP_B     (PREP_CONV + PP * HH)   // + 1,048,576 float2 items
#define PREP_TOT   (PREP_B + HH * PP)      // 4,980,736  (= 256 * 19456)

__global__ void prep_all(const float* __restrict__ hs, const float* __restrict__ Wi,
                         const float* __restrict__ Wg, const float* __restrict__ Wo,
                         const float* __restrict__ B_param, const float* __restrict__ C_param,
                         ushort* __restrict__ hsb, ushort* __restrict__ Wigb,
                         ushort* __restrict__ Wob, ushort* __restrict__ Bpkb,
                         ushort* __restrict__ Cpkb) {
    int i = blockIdx.x * 256 + threadIdx.x;
    if (i < PREP_CONV) {           // float4 convert regions
        const float4* s;
        ushort4* d;
        if (i < HS4)              { s = (const float4*)hs + i;  d = (ushort4*)hsb + i; }
        else if (i < HS4 + 2*W4)  { int j = i - HS4;
                                    s = (const float4*)(j < W4 ? Wi : Wg) + (j < W4 ? j : j - W4);
                                    d = (ushort4*)Wigb + j; }
        else                      { int j = i - HS4 - 2*W4;
                                    s = (const float4*)Wo + j; d = (ushort4*)Wob + j; }
        float4 v = *s;
        ushort4 o;
        o.x = f2bf(v.x); o.y = f2bf(v.y); o.z = f2bf(v.z); o.w = f2bf(v.w);
        *d = o;
    } else if (i < PREP_B) {       // B_param (P,H,2) -> Bpk (2P,H)
        int idx = i - PREP_CONV;
        int p = idx >> 10;
        int h = idx & 1023;
        float2 v = ((const float2*)B_param)[idx];
        Bpkb[(size_t)p * HH + h]        = f2bf(v.x);
        Bpkb[(size_t)(p + PP) * HH + h] = f2bf(v.y);
    } else {                       // C_param (H,P,2) -> Cpk (H,2P), im negated
        int idx = i - PREP_B;
        int h = idx >> 10;
        int p = idx & 1023;
        float2 v = ((const float2*)C_param)[idx];
        Cpkb[(size_t)h * C2 + p]      = f2bf(v.x);
        Cpkb[(size_t)h * C2 + PP + p] = f2bf(-v.y);
    }
}

// ---------------------------------------------------------------------------
// 8-phase 256-wide bf16 MFMA NT GEMM (round-7 proven, BM=256).
template<int BM, int STORE_BF16>
__global__ __launch_bounds__(512, 2) void gemm8p(
    const ushort* __restrict__ A, int lda,
    const ushort* __restrict__ B, int ldb,
    void* __restrict__ Cp, int ldc, int K, int nbx)
{
    constexpr int BN  = 256;
    constexpr int MR  = BM / 32;
    constexpr int MRH = MR / 2;
    constexpr int TA  = BM * 128;
    constexpr int TB  = BN * 128;
    __shared__ __align__(16) char smem[2 * TA + 2 * TB];

    const int bid = blockIdx.x;
    const int cpx = gridDim.x >> 3;
    const int wg  = (bid & 7) * cpx + (bid >> 3);
    const int by  = wg / nbx;
    const int bx  = wg - by * nbx;
    const int bm  = by * BM;
    const int bn  = bx * BN;

    const int tid  = threadIdx.x;
    const int wave = tid >> 6;
    const int lane = tid & 63;
    const int wr   = wave >> 2;
    const int wc   = wave & 3;
    const int lr   = lane & 15;
    const int kg   = lane >> 4;

    const int e  = (wave << 10) + ((lane << 4) ^ (((lane >> 3) & 7) << 4));
    const int r0 = e >> 7;
    const int c0 = (e & 127) >> 1;

    auto stA = [&](int bi, int u, int kt) {
        gload16(A + (size_t)(bm + u * 64 + r0) * lda + kt * 64 + c0,
                (ushort*)(smem + bi * TA + u * 8192 + (wave << 10)));
    };
    auto stB = [&](int bi, int u, int kt) {
        gload16(B + (size_t)(bn + u * 64 + r0) * ldb + kt * 64 + c0,
                (ushort*)(smem + 2 * TA + bi * TB + u * 8192 + (wave << 10)));
    };

    bf16x8 Af[MRH][2], Bf[4][2];
    auto ldsA = [&](int bi, int qm) {
#pragma unroll
        for (int f = 0; f < MRH; ++f)
#pragma unroll
            for (int kk = 0; kk < 2; ++kk) {
                int row = wr * (BM / 2) + qm * (BM / 4) + f * 16 + lr;
                int o = row * 128 + kk * 64 + kg * 16;
                o ^= (row & 7) << 4;
                Af[f][kk] = *(const bf16x8*)(smem + bi * TA + o);
            }
    };
    auto ldsBh = [&](int bi, int h) {   // h=0 -> Bf[0..1], h=1 -> Bf[2..3]
#pragma unroll
        for (int n = 0; n < 2; ++n)
#pragma unroll
            for (int kk = 0; kk < 2; ++kk) {
                int row = wc * 64 + (h * 2 + n) * 16 + lr;
                int o = row * 128 + kk * 64 + kg * 16;
                o ^= (row & 7) << 4;
                Bf[h * 2 + n][kk] = *(const bf16x8*)(smem + 2 * TA + bi * TB + o);
            }
    };

    f32x4 acc[MR][4];
#pragma unroll
    for (int m = 0; m < MR; ++m)
#pragma unroll
        for (int n = 0; n < 4; ++n)
#pragma unroll
            for (int i = 0; i < 4; ++i) acc[m][n][i] = 0.f;

    auto mfma16 = [&](int qm, int qn) {
        __builtin_amdgcn_s_setprio(1);
#pragma unroll
        for (int f = 0; f < MRH; ++f)
#pragma unroll
            for (int n2 = 0; n2 < 2; ++n2)
#pragma unroll
                for (int kk = 0; kk < 2; ++kk)
                    acc[qm * MRH + f][qn * 2 + n2] =
                        __builtin_amdgcn_mfma_f32_16x16x32_bf16(
                            Af[f][kk], Bf[qn * 2 + n2][kk],
                            acc[qm * MRH + f][qn * 2 + n2], 0, 0, 0);
        __builtin_amdgcn_s_setprio(0);
    };

    // prologue: buf0 full + buf1 B + buf1 A-early; vm6 lands buf0
    stA(0, 0, 0); stA(0, 1, 0); stA(0, 2, 0); stA(0, 3, 0);
    stB(0, 0, 0); stB(0, 1, 0); stB(0, 2, 0); stB(0, 3, 0);
    stB(1, 0, 1); stB(1, 1, 1); stB(1, 2, 1); stB(1, 3, 1);
    stA(1, 0, 1); stA(1, 2, 1);
    vm6();
    barrier_raw();

    const int nIter = K >> 7;
    for (int J = 0; J < nIter; ++J) {
        const bool pf  = (J + 1 < nIter);
        const int  kt1 = 2 * J + 1, kt2 = 2 * J + 2, kt3 = 2 * J + 3;
        // P1
        ldsA(0, 0); ldsBh(0, 0);
        stA(1, 1, kt1); stA(1, 3, kt1);
        lgk8();
        barrier_raw(); lgk0(); mfma16(0, 0); barrier_raw();
        // P2
        ldsBh(0, 1);
        barrier_raw(); lgk0(); mfma16(0, 1); barrier_raw();
        // P3
        ldsA(0, 1);
        if (pf) { stB(0, 0, kt2); stB(0, 1, kt2); stB(0, 2, kt2); stB(0, 3, kt2); }
        barrier_raw(); lgk0(); mfma16(1, 0); barrier_raw();
        // P4
        if (pf) { stA(0, 0, kt2); stA(0, 2, kt2); }
        barrier_raw(); lgk0(); mfma16(1, 1);
        if (pf) vm6(); else vm0();
        barrier_raw();
        // P5
        ldsA(1, 0); ldsBh(1, 0);
        if (pf) { stA(0, 1, kt2); stA(0, 3, kt2); }
        lgk8();
        barrier_raw(); lgk0(); mfma16(0, 0); barrier_raw();
        // P6
        ldsBh(1, 1);
        barrier_raw(); lgk0(); mfma16(0, 1); barrier_raw();
        // P7
        ldsA(1, 1);
        if (pf) { stB(1, 0, kt3); stB(1, 1, kt3); stB(1, 2, kt3); stB(1, 3, kt3); }
        barrier_raw(); lgk0(); mfma16(1, 0); barrier_raw();
        // P8
        if (pf) { stA(1, 0, kt3); stA(1, 2, kt3); }
        barrier_raw(); lgk0(); mfma16(1, 1);
        if (pf) vm6(); else vm0();
        barrier_raw();
    }

#pragma unroll
    for (int mf = 0; mf < MR; ++mf) {
#pragma unroll
        for (int n = 0; n < 4; ++n) {
            int col = bn + wc * 64 + n * 16 + lr;
#pragma unroll
            for (int i = 0; i < 4; ++i) {
                int row = bm + wr * (BM / 2) + mf * 16 + kg * 4 + i;
                float v = acc[mf][n][i];
                if (STORE_BF16)
                    ((ushort*)Cp)[(size_t)row * ldc + col] = f2bf(v);
                else
                    ((float*)Cp)[(size_t)row * ldc + col]  = v;
            }
        }
    }
}

// ---------------------------------------------------------------------------
// 2-blocks/CU occupancy-test GEMM: 128x128 tile, 4 waves (256 thr, 2Mx2N),
// BK=64, double-buffered LDS = 64 KiB -> 2 co-resident blocks per CU whose
// waves mutually hide barrier/vmcnt stalls (m97/m114 evidence).
// Schedule = gemm4p ported to 4-wave geometry (2 phases per K-tile):
//  Pa: ldsA(bt,q0)+ldsB(bt); stage B(b1,t+1) x4; bar; cl(0); lgk0; bar
//  Pb: ldsA(bt,q1);          stage A(b1,t+1) x4; bar; cl(1); lgk0; vm0; bar
// WAR: staged buffer b1's prior reads (tile t-1) drained at t-1's lgk0 +
//      barrier-pair before any stage touches it. RAW: vm0 lands tile t+1.
template<int STORE_BF16>
__global__ __launch_bounds__(256, 2) void gemm2b(
    const ushort* __restrict__ A, int lda,
    const ushort* __restrict__ B, int ldb,
    void* __restrict__ Cp, int ldc, int K, int nbx)
{
    constexpr int BM = 128, BN = 128;
    constexpr int TA = BM * 128;          // 16K bytes (128 rows x 128B)
    constexpr int TB = BN * 128;          // 16K bytes
    __shared__ __align__(16) char smem[2 * TA + 2 * TB];   // 64 KiB

    const int bid = blockIdx.x;
    const int cpx = gridDim.x >> 3;
    const int wg  = (bid & 7) * cpx + (bid >> 3);
    const int by  = wg / nbx;
    const int bx  = wg - by * nbx;
    const int bm  = by * BM;
    const int bn  = bx * BN;

    const int tid  = threadIdx.x;
    const int wave = tid >> 6;        // 0..3
    const int lane = tid & 63;
    const int wr   = wave >> 1;       // 0..1
    const int wc   = wave & 1;        // 0..1
    const int lr   = lane & 15;
    const int kg   = lane >> 4;

    // staging: one call = 256 lanes x 16B = 4KB = 32 rows; dest linear,
    // source pre-swizzled (same involution as read side: o ^= ((o>>7)&7)<<4)
    const int e  = (wave << 10) + ((lane << 4) ^ (((lane >> 3) & 7) << 4));
    const int r0 = e >> 7;            // 0..31 row within 32-row unit
    const int c0 = (e & 127) >> 1;    // col in bf16 elements

    auto stA = [&](int bi, int u, int kt) {
        gload16(A + (size_t)(bm + u * 32 + r0) * lda + kt * 64 + c0,
                (ushort*)(smem + bi * TA + u * 4096 + (wave << 10)));
    };
    auto stB = [&](int bi, int u, int kt) {
        gload16(B + (size_t)(bn + u * 32 + r0) * ldb + kt * 64 + c0,
                (ushort*)(smem + 2 * TA + bi * TB + u * 4096 + (wave << 10)));
    };

    bf16x8 Af[2][2], Bf[4][2];
    auto ldsA = [&](int bi, int qm) {
#pragma unroll
        for (int f = 0; f < 2; ++f)
#pragma unroll
            for (int kk = 0; kk < 2; ++kk) {
                int row = wr * 64 + qm * 32 + f * 16 + lr;
                int o = row * 128 + kk * 64 + kg * 16;
                o ^= (row & 7) << 4;
                Af[f][kk] = *(const bf16x8*)(smem + bi * TA + o);
            }
    };
    auto ldsB = [&](int bi) {
#pragma unroll
        for (int n = 0; n < 4; ++n)
#pragma unroll
            for (int kk = 0; kk < 2; ++kk) {
                int row = wc * 64 + n * 16 + lr;
                int o = row * 128 + kk * 64 + kg * 16;
                o ^= (row & 7) << 4;
                Bf[n][kk] = *(const bf16x8*)(smem + 2 * TA + bi * TB + o);
            }
    };

    f32x4 acc[4][4];
#pragma unroll
    for (int m = 0; m < 4; ++m)
#pragma unroll
        for (int n = 0; n < 4; ++n)
#pragma unroll
            for (int i = 0; i < 4; ++i) acc[m][n][i] = 0.f;

    auto cl = [&](int qm) {
        __builtin_amdgcn_s_setprio(1);
#pragma unroll
        for (int f = 0; f < 2; ++f)
#pragma unroll
            for (int n = 0; n < 4; ++n)
#pragma unroll
                for (int kk = 0; kk < 2; ++kk)
                    acc[qm * 2 + f][n] =
                        __builtin_amdgcn_mfma_f32_16x16x32_bf16(
                            Af[f][kk], Bf[n][kk], acc[qm * 2 + f][n], 0, 0, 0);
        __builtin_amdgcn_s_setprio(0);
    };

    // prologue: stage tile0 fully (8 calls), drain, barrier
    stA(0, 0, 0); stA(0, 1, 0); stA(0, 2, 0); stA(0, 3, 0);
    stB(0, 0, 0); stB(0, 1, 0); stB(0, 2, 0); stB(0, 3, 0);
    vm0();
    barrier_raw();

    const int nT = K >> 6;            // K-tiles of 64
    for (int t = 0; t < nT; ++t) {
        const int  bt = t & 1, b1 = bt ^ 1;
        const bool pf = (t + 1 < nT);
        // Pa
        ldsA(bt, 0); ldsB(bt);
        if (pf) { stB(b1, 0, t + 1); stB(b1, 1, t + 1);
                  stB(b1, 2, t + 1); stB(b1, 3, t + 1); }
        barrier_raw();
        cl(0);
        lgk0();
        barrier_raw();
        // Pb
        ldsA(bt, 1);
        if (pf) { stA(b1, 0, t + 1); stA(b1, 1, t + 1);
                  stA(b1, 2, t + 1); stA(b1, 3, t + 1); }
        barrier_raw();
        cl(1);
        lgk0();
        if (pf) vm0();
        barrier_raw();
    }

    // epilogue: D row = (lane>>4)*4 + i, col = lane&15 per fragment
#pragma unroll
    for (int mf = 0; mf < 4; ++mf) {
#pragma unroll
        for (int n = 0; n < 4; ++n) {
            int col = bn + wc * 64 + n * 16 + lr;
#pragma unroll
            for (int i = 0; i < 4; ++i) {
                int row = bm + wr * 64 + mf * 16 + kg * 4 + i;
                float v = acc[mf][n][i];
                if (STORE_BF16)
                    ((ushort*)Cp)[(size_t)row * ldc + col] = f2bf(v);
                else
                    ((float*)Cp)[(size_t)row * ldc + col]  = v;
            }
        }
    }
}

// ---------------------------------------------------------------------------
// Scan (fp32 state, bf16 Bu), chunk-parallel: passA -> combine -> passB
__device__ __forceinline__ void linoss_coeffs(const float* A_diag, const float* dt_p,
                                              int p, float& m11, float& m12,
                                              float& m21, float& m22,
                                              float& f1, float& f2) {
    float A  = fmaxf(A_diag[p], 0.f);
    float dt = 1.f / (1.f + expf(-dt_p[p]));
    float S  = 1.f / (1.f + dt * dt * A);
    m11 = S;        m12 = -dt * A * S;
    m21 = dt * S;   m22 = S;
    f1  = dt * S;   f2  = dt * dt * S;
}

__global__ void scan_passA(const ushort* __restrict__ Bu,
                           const float* __restrict__ A_diag,
                           const float* __restrict__ dt_p,
                           float2* __restrict__ sEnd) {
    int c = blockIdx.x * 256 + threadIdx.x;
    int b = blockIdx.y;
    int j = blockIdx.z;
    float m11, m12, m21, m22, f1, f2;
    linoss_coeffs(A_diag, dt_p, c & 1023, m11, m12, m21, m22, f1, f2);
    const ushort* bu = Bu + ((size_t)(b * TT + j * LCH)) * C2 + c;
    float z = 0.f, y = 0.f;
#pragma unroll 8
    for (int i = 0; i < LCH; ++i) {
        float u  = bf2f(bu[(size_t)i * C2]);
        float z1 = m11 * z + m12 * y + f1 * u;
        float y1 = m21 * z + m22 * y + f2 * u;
        z = z1; y = y1;
    }
    sEnd[((size_t)j * BB + b) * C2 + c] = make_float2(z, y);
}

__global__ void scan_combine(const float* __restrict__ A_diag,
                             const float* __restrict__ dt_p,
                             const float2* __restrict__ sEnd,
                             float2* __restrict__ sInit) {
    int idx = blockIdx.x * 256 + threadIdx.x;   // 0..8191
    int c = idx & (C2 - 1);
    int b = idx >> 11;
    float m11, m12, m21, m22, f1, f2;
    linoss_coeffs(A_diag, dt_p, c & 1023, m11, m12, m21, m22, f1, f2);
    float e11 = m11, e12 = m12, e21 = m21, e22 = m22;   // M^32 by 5 squarings
#pragma unroll
    for (int s = 0; s < 5; ++s) {
        float n11 = e11 * e11 + e12 * e21;
        float n12 = e11 * e12 + e12 * e22;
        float n21 = e21 * e11 + e22 * e21;
        float n22 = e21 * e12 + e22 * e22;
        e11 = n11; e12 = n12; e21 = n21; e22 = n22;
    }
    float z = 0.f, y = 0.f;
    for (int j = 0; j < NC; ++j) {
        size_t off = ((size_t)j * BB + b) * C2 + c;
        sInit[off] = make_float2(z, y);
        float2 le = sEnd[off];
        float z1 = e11 * z + e12 * y + le.x;
        float y1 = e21 * z + e22 * y + le.y;
        z = z1; y = y1;
    }
}

__global__ void scan_passB(const ushort* __restrict__ Bu,
                           const float* __restrict__ A_diag,
                           const float* __restrict__ dt_p,
                           const float2* __restrict__ sInit,
                           ushort* __restrict__ YSb) {
    int c = blockIdx.x * 256 + threadIdx.x;
    int b = blockIdx.y;
    int j = blockIdx.z;
    float m11, m12, m21, m22, f1, f2;
    linoss_coeffs(A_diag, dt_p, c & 1023, m11, m12, m21, m22, f1, f2);
    float2 s0 = sInit[((size_t)j * BB + b) * C2 + c];
    float z = s0.x, y = s0.y;
    const ushort* bu = Bu  + ((size_t)(b * TT + j * LCH)) * C2 + c;
    ushort*       ys = YSb + ((size_t)(b * TT + j * LCH)) * C2 + c;
#pragma unroll 8
    for (int i = 0; i < LCH; ++i) {
        float u  = bf2f(bu[(size_t)i * C2]);
        float z1 = m11 * z + m12 * y + f1 * u;
        float y1 = m21 * z + m22 * y + f2 * u;
        z = z1; y = y1;
        ys[(size_t)i * C2] = f2bf(y);
    }
}

// ---------------------------------------------------------------------------
// Fused epilogue: o = O(bf16) + D*x ; rms-normalize ; * nw * swish(g) -> V
__global__ void rmsgate_kernel(const ushort* __restrict__ O,
                               const ushort* __restrict__ XGb,
                               const float* __restrict__ Dv,
                               const float* __restrict__ nw,
                               ushort* __restrict__ V) {
    int m = blockIdx.x;
    int t = threadIdx.x;
    ushort4 o4 = ((const ushort4*)(O + (size_t)m * HH))[t];
    ushort4 x4 = ((const ushort4*)(XGb + (size_t)m * C2))[t];
    float4  d4 = ((const float4*)Dv)[t];
    float of[4];
    of[0] = bf2f(o4.x) + d4.x * bf2f(x4.x);
    of[1] = bf2f(o4.y) + d4.y * bf2f(x4.y);
    of[2] = bf2f(o4.z) + d4.z * bf2f(x4.z);
    of[3] = bf2f(o4.w) + d4.w * bf2f(x4.w);
    float ss = of[0]*of[0] + of[1]*of[1] + of[2]*of[2] + of[3]*of[3];
#pragma unroll
    for (int o = 32; o > 0; o >>= 1) ss += __shfl_down(ss, o);
    __shared__ float wsum[4];
    if ((t & 63) == 0) wsum[t >> 6] = ss;
    __syncthreads();
    float tot = wsum[0] + wsum[1] + wsum[2] + wsum[3];
    float r = rsqrtf(tot * (1.f / (float)HH) + 1e-5f);

    ushort4 g4 = ((const ushort4*)(XGb + (size_t)m * C2 + HH))[t];
    float4  w4 = ((const float4*)nw)[t];
    float g[4] = {bf2f(g4.x), bf2f(g4.y), bf2f(g4.z), bf2f(g4.w)};
    float w[4] = {w4.x, w4.y, w4.z, w4.w};
    ushort4 vout;
    ushort* vo = &vout.x;
#pragma unroll
    for (int i = 0; i < 4; ++i) {
        float sw = g[i] / (1.f + expf(-g[i]));
        vo[i] = f2bf(of[i] * r * w[i] * sw);
    }
    ((ushort4*)(V + (size_t)m * HH))[t] = vout;
}

// ---------------------------------------------------------------------------
extern "C" void kernel_launch(void* const* d_in, const int* in_sizes, int n_in,
                              void* d_out, int out_size, void* d_ws, size_t ws_size,
                              hipStream_t stream) {
    const float* hs      = (const float*)d_in[0];
    const float* Wi      = (const float*)d_in[1];
    const float* Wg      = (const float*)d_in[2];
    const float* Wo      = (const float*)d_in[3];
    const float* A_diag  = (const float*)d_in[4];
    const float* B_param = (const float*)d_in[5];
    const float* C_param = (const float*)d_in[6];
    const float* Dv      = (const float*)d_in[7];
    const float* dtp     = (const float*)d_in[8];
    const float* nw      = (const float*)d_in[9];
    float* out = (float*)d_out;

    char* ws = (char*)d_ws;
    ushort* hsb  = (ushort*)ws;                                   ws += (size_t)MT * HH * 2;   // 16 MB
    ushort* Wigb = (ushort*)ws;                                   ws += (size_t)C2 * HH * 2;   //  4 MB
    ushort* Wob  = (ushort*)ws;                                   ws += (size_t)HH * HH * 2;   //  2 MB
    ushort* Bpkb = (ushort*)ws;                                   ws += (size_t)C2 * HH * 2;   //  4 MB
    ushort* Cpkb = (ushort*)ws;                                   ws += (size_t)HH * C2 * 2;   //  4 MB
    ushort* XGb  = (ushort*)ws;                                   ws += (size_t)MT * C2 * 2;   // 32 MB
    ushort* Bu   = (ushort*)ws;                                   ws += (size_t)MT * C2 * 2;   // 32 MB
    ushort* YSb  = (ushort*)ws;                                   ws += (size_t)MT * C2 * 2;   // 32 MB
    ushort* O    = (ushort*)ws;                                   ws += (size_t)MT * HH * 2;   // 16 MB
    ushort* Vb   = (ushort*)ws;                                   ws += (size_t)MT * HH * 2;   // 16 MB
    float2* sEnd  = (float2*)ws;                                  ws += (size_t)NC * BB * C2 * 8;
    float2* sInit = (float2*)ws;

    dim3 blk(256);

    // single fused prep kernel (converts + repacks)
    prep_all<<<dim3(PREP_TOT / 256), blk, 0, stream>>>(
        hs, Wi, Wg, Wo, B_param, C_param, hsb, Wigb, Wob, Bpkb, Cpkb);

    // XG = hs @ [Wi|Wg]^T   (M=8192, N=2048, K=1024) -> bf16
    gemm8p<256, 1><<<dim3(256), dim3(512), 0, stream>>>(
        hsb, HH, Wigb, HH, XGb, C2, HH, 8);

    // Bu = x @ Bpk^T        (M=8192, N=2048, K=1024) -> bf16
    gemm8p<256, 1><<<dim3(256), dim3(512), 0, stream>>>(
        XGb, C2, Bpkb, HH, Bu, C2, HH, 8);

    // chunked linear scan (fp32 state over bf16 Bu), YS emitted as bf16
    scan_passA<<<dim3(C2 / 256, BB, NC), blk, 0, stream>>>(Bu, A_diag, dtp, sEnd);
    scan_combine<<<dim3((BB * C2) / 256), blk, 0, stream>>>(A_diag, dtp, sEnd, sInit);
    scan_passB<<<dim3(C2 / 256, BB, NC), blk, 0, stream>>>(Bu, A_diag, dtp, sInit, YSb);

    // O = YS @ Cpk^T        (M=8192, N=1024, K=2048) -> bf16 (2-blocks/CU kernel)
    gemm2b<1><<<dim3(512), dim3(256), 0, stream>>>(
        YSb, C2, Cpkb, C2, O, HH, C2, 8);

    // fused D*x + RMSNorm + swish gate -> V (bf16)
    rmsgate_kernel<<<dim3(MT), blk, 0, stream>>>(O, XGb, Dv, nw, Vb);

    // out = V @ Wo^T        (M=8192, N=1024, K=1024) -> fp32 (2-blocks/CU kernel)
    gemm2b<0><<<dim3(512), dim3(256), 0, stream>>>(
        Vb, HH, Wob, HH, out, HH, HH, 8);
}

// Round 10
// 187.346 us; speedup vs baseline: 1.0906x; 1.0029x over previous
//
#include <hip/hip_runtime.h>
#include <hip/hip_bf16.h>
#include <math.h>

// Problem constants
#define BB 4
#define TT 2048
#define HH 1024      // HID == H == P == 1024
#define PP 1024
#define MT 8192      // BB*TT rows
#define C2 2048      // packed re/im columns
#define NC 64        // scan chunks
#define LCH 32       // chunk length (TT/NC)

typedef __attribute__((ext_vector_type(8))) short  bf16x8;
typedef __attribute__((ext_vector_type(4))) float  f32x4;

__device__ __forceinline__ ushort f2bf(float f) {
    union { float f; unsigned u; } v; v.f = f;
    unsigned r = v.u + 0x7fffu + ((v.u >> 16) & 1u);   // RNE
    return (ushort)(r >> 16);
}
__device__ __forceinline__ float bf2f(ushort h) {
    union { unsigned u; float f; } v; v.u = ((unsigned)h) << 16;
    return v.f;
}

// async global -> LDS, 16B per lane (dest = wave-uniform base + lane*16)
__device__ __forceinline__ void gload16(const ushort* g, ushort* l) {
    __builtin_amdgcn_global_load_lds((const __attribute__((address_space(1))) void*)g,
                                     (__attribute__((address_space(3))) void*)l,
                                     16, 0, 0);
}
__device__ __forceinline__ void barrier_raw() { __builtin_amdgcn_s_barrier(); }
__device__ __forceinline__ void lgk0() { asm volatile("s_waitcnt lgkmcnt(0)" ::: "memory"); }
__device__ __forceinline__ void lgk8() { asm volatile("s_waitcnt lgkmcnt(8)" ::: "memory"); }
__device__ __forceinline__ void vm6()  { asm volatile("s_waitcnt vmcnt(6)"   ::: "memory"); }
__device__ __forceinline__ void vm0()  { asm volatile("s_waitcnt vmcnt(0)"   ::: "memory"); }

// ---------------------------------------------------------------------------
// single fused prep kernel: fp32->bf16 converts (hs, Wi|Wg, Wo) + B/C repacks
#define HS4   (MT * HH / 4)          // 2,097,152 float4 items
#define W4    (HH * HH / 4)          // 262,144 float4 items
#define PREP_CONV  (HS4 + 3 * W4)    // 2,883,584
#define PREP_B     (PREP_CONV + PP * HH)   // + 1,048,576 float2 items
#define PREP_TOT   (PREP_B + HH * PP)      // 4,980,736  (= 256 * 19456)

__global__ void prep_all(const float* __restrict__ hs, const float* __restrict__ Wi,
                         const float* __restrict__ Wg, const float* __restrict__ Wo,
                         const float* __restrict__ B_param, const float* __restrict__ C_param,
                         ushort* __restrict__ hsb, ushort* __restrict__ Wigb,
                         ushort* __restrict__ Wob, ushort* __restrict__ Bpkb,
                         ushort* __restrict__ Cpkb) {
    int i = blockIdx.x * 256 + threadIdx.x;
    if (i < PREP_CONV) {           // float4 convert regions
        const float4* s;
        ushort4* d;
        if (i < HS4)              { s = (const float4*)hs + i;  d = (ushort4*)hsb + i; }
        else if (i < HS4 + 2*W4)  { int j = i - HS4;
                                    s = (const float4*)(j < W4 ? Wi : Wg) + (j < W4 ? j : j - W4);
                                    d = (ushort4*)Wigb + j; }
        else                      { int j = i - HS4 - 2*W4;
                                    s = (const float4*)Wo + j; d = (ushort4*)Wob + j; }
        float4 v = *s;
        ushort4 o;
        o.x = f2bf(v.x); o.y = f2bf(v.y); o.z = f2bf(v.z); o.w = f2bf(v.w);
        *d = o;
    } else if (i < PREP_B) {       // B_param (P,H,2) -> Bpk (2P,H)
        int idx = i - PREP_CONV;
        int p = idx >> 10;
        int h = idx & 1023;
        float2 v = ((const float2*)B_param)[idx];
        Bpkb[(size_t)p * HH + h]        = f2bf(v.x);
        Bpkb[(size_t)(p + PP) * HH + h] = f2bf(v.y);
    } else {                       // C_param (H,P,2) -> Cpk (H,2P), im negated
        int idx = i - PREP_B;
        int h = idx >> 10;
        int p = idx & 1023;
        float2 v = ((const float2*)C_param)[idx];
        Cpkb[(size_t)h * C2 + p]      = f2bf(v.x);
        Cpkb[(size_t)h * C2 + PP + p] = f2bf(-v.y);
    }
}

// ---------------------------------------------------------------------------
// 8-phase 256-wide bf16 MFMA NT GEMM (round-7 proven, BM=256). CONTROL arm
// of this round's A/B: Bu GEMM runs here.
template<int BM, int STORE_BF16>
__global__ __launch_bounds__(512, 2) void gemm8p(
    const ushort* __restrict__ A, int lda,
    const ushort* __restrict__ B, int ldb,
    void* __restrict__ Cp, int ldc, int K, int nbx)
{
    constexpr int BN  = 256;
    constexpr int MR  = BM / 32;
    constexpr int MRH = MR / 2;
    constexpr int TA  = BM * 128;
    constexpr int TB  = BN * 128;
    __shared__ __align__(16) char smem[2 * TA + 2 * TB];

    const int bid = blockIdx.x;
    const int cpx = gridDim.x >> 3;
    const int wg  = (bid & 7) * cpx + (bid >> 3);
    const int by  = wg / nbx;
    const int bx  = wg - by * nbx;
    const int bm  = by * BM;
    const int bn  = bx * BN;

    const int tid  = threadIdx.x;
    const int wave = tid >> 6;
    const int lane = tid & 63;
    const int wr   = wave >> 2;
    const int wc   = wave & 3;
    const int lr   = lane & 15;
    const int kg   = lane >> 4;

    const int e  = (wave << 10) + ((lane << 4) ^ (((lane >> 3) & 7) << 4));
    const int r0 = e >> 7;
    const int c0 = (e & 127) >> 1;

    auto stA = [&](int bi, int u, int kt) {
        gload16(A + (size_t)(bm + u * 64 + r0) * lda + kt * 64 + c0,
                (ushort*)(smem + bi * TA + u * 8192 + (wave << 10)));
    };
    auto stB = [&](int bi, int u, int kt) {
        gload16(B + (size_t)(bn + u * 64 + r0) * ldb + kt * 64 + c0,
                (ushort*)(smem + 2 * TA + bi * TB + u * 8192 + (wave << 10)));
    };

    bf16x8 Af[MRH][2], Bf[4][2];
    auto ldsA = [&](int bi, int qm) {
#pragma unroll
        for (int f = 0; f < MRH; ++f)
#pragma unroll
            for (int kk = 0; kk < 2; ++kk) {
                int row = wr * (BM / 2) + qm * (BM / 4) + f * 16 + lr;
                int o = row * 128 + kk * 64 + kg * 16;
                o ^= (row & 7) << 4;
                Af[f][kk] = *(const bf16x8*)(smem + bi * TA + o);
            }
    };
    auto ldsBh = [&](int bi, int h) {   // h=0 -> Bf[0..1], h=1 -> Bf[2..3]
#pragma unroll
        for (int n = 0; n < 2; ++n)
#pragma unroll
            for (int kk = 0; kk < 2; ++kk) {
                int row = wc * 64 + (h * 2 + n) * 16 + lr;
                int o = row * 128 + kk * 64 + kg * 16;
                o ^= (row & 7) << 4;
                Bf[h * 2 + n][kk] = *(const bf16x8*)(smem + 2 * TA + bi * TB + o);
            }
    };

    f32x4 acc[MR][4];
#pragma unroll
    for (int m = 0; m < MR; ++m)
#pragma unroll
        for (int n = 0; n < 4; ++n)
#pragma unroll
            for (int i = 0; i < 4; ++i) acc[m][n][i] = 0.f;

    auto mfma16 = [&](int qm, int qn) {
        __builtin_amdgcn_s_setprio(1);
#pragma unroll
        for (int f = 0; f < MRH; ++f)
#pragma unroll
            for (int n2 = 0; n2 < 2; ++n2)
#pragma unroll
                for (int kk = 0; kk < 2; ++kk)
                    acc[qm * MRH + f][qn * 2 + n2] =
                        __builtin_amdgcn_mfma_f32_16x16x32_bf16(
                            Af[f][kk], Bf[qn * 2 + n2][kk],
                            acc[qm * MRH + f][qn * 2 + n2], 0, 0, 0);
        __builtin_amdgcn_s_setprio(0);
    };

    // prologue: buf0 full + buf1 B + buf1 A-early; vm6 lands buf0
    stA(0, 0, 0); stA(0, 1, 0); stA(0, 2, 0); stA(0, 3, 0);
    stB(0, 0, 0); stB(0, 1, 0); stB(0, 2, 0); stB(0, 3, 0);
    stB(1, 0, 1); stB(1, 1, 1); stB(1, 2, 1); stB(1, 3, 1);
    stA(1, 0, 1); stA(1, 2, 1);
    vm6();
    barrier_raw();

    const int nIter = K >> 7;
    for (int J = 0; J < nIter; ++J) {
        const bool pf  = (J + 1 < nIter);
        const int  kt1 = 2 * J + 1, kt2 = 2 * J + 2, kt3 = 2 * J + 3;
        // P1
        ldsA(0, 0); ldsBh(0, 0);
        stA(1, 1, kt1); stA(1, 3, kt1);
        lgk8();
        barrier_raw(); lgk0(); mfma16(0, 0); barrier_raw();
        // P2
        ldsBh(0, 1);
        barrier_raw(); lgk0(); mfma16(0, 1); barrier_raw();
        // P3
        ldsA(0, 1);
        if (pf) { stB(0, 0, kt2); stB(0, 1, kt2); stB(0, 2, kt2); stB(0, 3, kt2); }
        barrier_raw(); lgk0(); mfma16(1, 0); barrier_raw();
        // P4
        if (pf) { stA(0, 0, kt2); stA(0, 2, kt2); }
        barrier_raw(); lgk0(); mfma16(1, 1);
        if (pf) vm6(); else vm0();
        barrier_raw();
        // P5
        ldsA(1, 0); ldsBh(1, 0);
        if (pf) { stA(0, 1, kt2); stA(0, 3, kt2); }
        lgk8();
        barrier_raw(); lgk0(); mfma16(0, 0); barrier_raw();
        // P6
        ldsBh(1, 1);
        barrier_raw(); lgk0(); mfma16(0, 1); barrier_raw();
        // P7
        ldsA(1, 1);
        if (pf) { stB(1, 0, kt3); stB(1, 1, kt3); stB(1, 2, kt3); stB(1, 3, kt3); }
        barrier_raw(); lgk0(); mfma16(1, 0); barrier_raw();
        // P8
        if (pf) { stA(1, 0, kt3); stA(1, 2, kt3); }
        barrier_raw(); lgk0(); mfma16(1, 1);
        if (pf) vm6(); else vm0();
        barrier_raw();
    }

#pragma unroll
    for (int mf = 0; mf < MR; ++mf) {
#pragma unroll
        for (int n = 0; n < 4; ++n) {
            int col = bn + wc * 64 + n * 16 + lr;
#pragma unroll
            for (int i = 0; i < 4; ++i) {
                int row = bm + wr * (BM / 2) + mf * 16 + kg * 4 + i;
                float v = acc[mf][n][i];
                if (STORE_BF16)
                    ((ushort*)Cp)[(size_t)row * ldc + col] = f2bf(v);
                else
                    ((float*)Cp)[(size_t)row * ldc + col]  = v;
            }
        }
    }
}

// ---------------------------------------------------------------------------
// 2-blocks/CU GEMM: 128x128 tile, 4 waves (256 thr, 2Mx2N), BK=64,
// double-buffered LDS = 64 KiB -> 2 co-resident blocks per CU. TREATMENT arm:
// XG (N=2048) runs here this round, plus C-proj and out-proj (proven r9).
template<int STORE_BF16>
__global__ __launch_bounds__(256, 2) void gemm2b(
    const ushort* __restrict__ A, int lda,
    const ushort* __restrict__ B, int ldb,
    void* __restrict__ Cp, int ldc, int K, int nbx)
{
    constexpr int BM = 128, BN = 128;
    constexpr int TA = BM * 128;          // 16K bytes
    constexpr int TB = BN * 128;          // 16K bytes
    __shared__ __align__(16) char smem[2 * TA + 2 * TB];   // 64 KiB

    const int bid = blockIdx.x;
    const int cpx = gridDim.x >> 3;
    const int wg  = (bid & 7) * cpx + (bid >> 3);
    const int by  = wg / nbx;
    const int bx  = wg - by * nbx;
    const int bm  = by * BM;
    const int bn  = bx * BN;

    const int tid  = threadIdx.x;
    const int wave = tid >> 6;        // 0..3
    const int lane = tid & 63;
    const int wr   = wave >> 1;       // 0..1
    const int wc   = wave & 1;        // 0..1
    const int lr   = lane & 15;
    const int kg   = lane >> 4;

    const int e  = (wave << 10) + ((lane << 4) ^ (((lane >> 3) & 7) << 4));
    const int r0 = e >> 7;            // 0..31 row within 32-row unit
    const int c0 = (e & 127) >> 1;    // col in bf16 elements

    auto stA = [&](int bi, int u, int kt) {
        gload16(A + (size_t)(bm + u * 32 + r0) * lda + kt * 64 + c0,
                (ushort*)(smem + bi * TA + u * 4096 + (wave << 10)));
    };
    auto stB = [&](int bi, int u, int kt) {
        gload16(B + (size_t)(bn + u * 32 + r0) * ldb + kt * 64 + c0,
                (ushort*)(smem + 2 * TA + bi * TB + u * 4096 + (wave << 10)));
    };

    bf16x8 Af[2][2], Bf[4][2];
    auto ldsA = [&](int bi, int qm) {
#pragma unroll
        for (int f = 0; f < 2; ++f)
#pragma unroll
            for (int kk = 0; kk < 2; ++kk) {
                int row = wr * 64 + qm * 32 + f * 16 + lr;
                int o = row * 128 + kk * 64 + kg * 16;
                o ^= (row & 7) << 4;
                Af[f][kk] = *(const bf16x8*)(smem + bi * TA + o);
            }
    };
    auto ldsB = [&](int bi) {
#pragma unroll
        for (int n = 0; n < 4; ++n)
#pragma unroll
            for (int kk = 0; kk < 2; ++kk) {
                int row = wc * 64 + n * 16 + lr;
                int o = row * 128 + kk * 64 + kg * 16;
                o ^= (row & 7) << 4;
                Bf[n][kk] = *(const bf16x8*)(smem + 2 * TA + bi * TB + o);
            }
    };

    f32x4 acc[4][4];
#pragma unroll
    for (int m = 0; m < 4; ++m)
#pragma unroll
        for (int n = 0; n < 4; ++n)
#pragma unroll
            for (int i = 0; i < 4; ++i) acc[m][n][i] = 0.f;

    auto cl = [&](int qm) {
        __builtin_amdgcn_s_setprio(1);
#pragma unroll
        for (int f = 0; f < 2; ++f)
#pragma unroll
            for (int n = 0; n < 4; ++n)
#pragma unroll
                for (int kk = 0; kk < 2; ++kk)
                    acc[qm * 2 + f][n] =
                        __builtin_amdgcn_mfma_f32_16x16x32_bf16(
                            Af[f][kk], Bf[n][kk], acc[qm * 2 + f][n], 0, 0, 0);
        __builtin_amdgcn_s_setprio(0);
    };

    // prologue: stage tile0 fully (8 calls), drain, barrier
    stA(0, 0, 0); stA(0, 1, 0); stA(0, 2, 0); stA(0, 3, 0);
    stB(0, 0, 0); stB(0, 1, 0); stB(0, 2, 0); stB(0, 3, 0);
    vm0();
    barrier_raw();

    const int nT = K >> 6;            // K-tiles of 64
    for (int t = 0; t < nT; ++t) {
        const int  bt = t & 1, b1 = bt ^ 1;
        const bool pf = (t + 1 < nT);
        // Pa
        ldsA(bt, 0); ldsB(bt);
        if (pf) { stB(b1, 0, t + 1); stB(b1, 1, t + 1);
                  stB(b1, 2, t + 1); stB(b1, 3, t + 1); }
        barrier_raw();
        cl(0);
        lgk0();
        barrier_raw();
        // Pb
        ldsA(bt, 1);
        if (pf) { stA(b1, 0, t + 1); stA(b1, 1, t + 1);
                  stA(b1, 2, t + 1); stA(b1, 3, t + 1); }
        barrier_raw();
        cl(1);
        lgk0();
        if (pf) vm0();
        barrier_raw();
    }

    // epilogue: D row = (lane>>4)*4 + i, col = lane&15 per fragment
#pragma unroll
    for (int mf = 0; mf < 4; ++mf) {
#pragma unroll
        for (int n = 0; n < 4; ++n) {
            int col = bn + wc * 64 + n * 16 + lr;
#pragma unroll
            for (int i = 0; i < 4; ++i) {
                int row = bm + wr * 64 + mf * 16 + kg * 4 + i;
                float v = acc[mf][n][i];
                if (STORE_BF16)
                    ((ushort*)Cp)[(size_t)row * ldc + col] = f2bf(v);
                else
                    ((float*)Cp)[(size_t)row * ldc + col]  = v;
            }
        }
    }
}

// ---------------------------------------------------------------------------
// Scan (fp32 state, bf16 Bu), chunk-parallel: passA -> combine -> passB
__device__ __forceinline__ void linoss_coeffs(const float* A_diag, const float* dt_p,
                                              int p, float& m11, float& m12,
                                              float& m21, float& m22,
                                              float& f1, float& f2) {
    float A  = fmaxf(A_diag[p], 0.f);
    float dt = 1.f / (1.f + expf(-dt_p[p]));
    float S  = 1.f / (1.f + dt * dt * A);
    m11 = S;        m12 = -dt * A * S;
    m21 = dt * S;   m22 = S;
    f1  = dt * S;   f2  = dt * dt * S;
}

__global__ void scan_passA(const ushort* __restrict__ Bu,
                           const float* __restrict__ A_diag,
                           const float* __restrict__ dt_p,
                           float2* __restrict__ sEnd) {
    int c = blockIdx.x * 256 + threadIdx.x;
    int b = blockIdx.y;
    int j = blockIdx.z;
    float m11, m12, m21, m22, f1, f2;
    linoss_coeffs(A_diag, dt_p, c & 1023, m11, m12, m21, m22, f1, f2);
    const ushort* bu = Bu + ((size_t)(b * TT + j * LCH)) * C2 + c;
    float z = 0.f, y = 0.f;
#pragma unroll 8
    for (int i = 0; i < LCH; ++i) {
        float u  = bf2f(bu[(size_t)i * C2]);
        float z1 = m11 * z + m12 * y + f1 * u;
        float y1 = m21 * z + m22 * y + f2 * u;
        z = z1; y = y1;
    }
    sEnd[((size_t)j * BB + b) * C2 + c] = make_float2(z, y);
}

__global__ void scan_combine(const float* __restrict__ A_diag,
                             const float* __restrict__ dt_p,
                             const float2* __restrict__ sEnd,
                             float2* __restrict__ sInit) {
    int idx = blockIdx.x * 256 + threadIdx.x;   // 0..8191
    int c = idx & (C2 - 1);
    int b = idx >> 11;
    float m11, m12, m21, m22, f1, f2;
    linoss_coeffs(A_diag, dt_p, c & 1023, m11, m12, m21, m22, f1, f2);
    float e11 = m11, e12 = m12, e21 = m21, e22 = m22;   // M^32 by 5 squarings
#pragma unroll
    for (int s = 0; s < 5; ++s) {
        float n11 = e11 * e11 + e12 * e21;
        float n12 = e11 * e12 + e12 * e22;
        float n21 = e21 * e11 + e22 * e21;
        float n22 = e21 * e12 + e22 * e22;
        e11 = n11; e12 = n12; e21 = n21; e22 = n22;
    }
    float z = 0.f, y = 0.f;
    for (int j = 0; j < NC; ++j) {
        size_t off = ((size_t)j * BB + b) * C2 + c;
        sInit[off] = make_float2(z, y);
        float2 le = sEnd[off];
        float z1 = e11 * z + e12 * y + le.x;
        float y1 = e21 * z + e22 * y + le.y;
        z = z1; y = y1;
    }
}

__global__ void scan_passB(const ushort* __restrict__ Bu,
                           const float* __restrict__ A_diag,
                           const float* __restrict__ dt_p,
                           const float2* __restrict__ sInit,
                           ushort* __restrict__ YSb) {
    int c = blockIdx.x * 256 + threadIdx.x;
    int b = blockIdx.y;
    int j = blockIdx.z;
    float m11, m12, m21, m22, f1, f2;
    linoss_coeffs(A_diag, dt_p, c & 1023, m11, m12, m21, m22, f1, f2);
    float2 s0 = sInit[((size_t)j * BB + b) * C2 + c];
    float z = s0.x, y = s0.y;
    const ushort* bu = Bu  + ((size_t)(b * TT + j * LCH)) * C2 + c;
    ushort*       ys = YSb + ((size_t)(b * TT + j * LCH)) * C2 + c;
#pragma unroll 8
    for (int i = 0; i < LCH; ++i) {
        float u  = bf2f(bu[(size_t)i * C2]);
        float z1 = m11 * z + m12 * y + f1 * u;
        float y1 = m21 * z + m22 * y + f2 * u;
        z = z1; y = y1;
        ys[(size_t)i * C2] = f2bf(y);
    }
}

// ---------------------------------------------------------------------------
// Fused epilogue: o = O(bf16) + D*x ; rms-normalize ; * nw * swish(g) -> V
__global__ void rmsgate_kernel(const ushort* __restrict__ O,
                               const ushort* __restrict__ XGb,
                               const float* __restrict__ Dv,
                               const float* __restrict__ nw,
                               ushort* __restrict__ V) {
    int m = blockIdx.x;
    int t = threadIdx.x;
    ushort4 o4 = ((const ushort4*)(O + (size_t)m * HH))[t];
    ushort4 x4 = ((const ushort4*)(XGb + (size_t)m * C2))[t];
    float4  d4 = ((const float4*)Dv)[t];
    float of[4];
    of[0] = bf2f(o4.x) + d4.x * bf2f(x4.x);
    of[1] = bf2f(o4.y) + d4.y * bf2f(x4.y);
    of[2] = bf2f(o4.z) + d4.z * bf2f(x4.z);
    of[3] = bf2f(o4.w) + d4.w * bf2f(x4.w);
    float ss = of[0]*of[0] + of[1]*of[1] + of[2]*of[2] + of[3]*of[3];
#pragma unroll
    for (int o = 32; o > 0; o >>= 1) ss += __shfl_down(ss, o);
    __shared__ float wsum[4];
    if ((t & 63) == 0) wsum[t >> 6] = ss;
    __syncthreads();
    float tot = wsum[0] + wsum[1] + wsum[2] + wsum[3];
    float r = rsqrtf(tot * (1.f / (float)HH) + 1e-5f);

    ushort4 g4 = ((const ushort4*)(XGb + (size_t)m * C2 + HH))[t];
    float4  w4 = ((const float4*)nw)[t];
    float g[4] = {bf2f(g4.x), bf2f(g4.y), bf2f(g4.z), bf2f(g4.w)};
    float w[4] = {w4.x, w4.y, w4.z, w4.w};
    ushort4 vout;
    ushort* vo = &vout.x;
#pragma unroll
    for (int i = 0; i < 4; ++i) {
        float sw = g[i] / (1.f + expf(-g[i]));
        vo[i] = f2bf(of[i] * r * w[i] * sw);
    }
    ((ushort4*)(V + (size_t)m * HH))[t] = vout;
}

// ---------------------------------------------------------------------------
extern "C" void kernel_launch(void* const* d_in, const int* in_sizes, int n_in,
                              void* d_out, int out_size, void* d_ws, size_t ws_size,
                              hipStream_t stream) {
    const float* hs      = (const float*)d_in[0];
    const float* Wi      = (const float*)d_in[1];
    const float* Wg      = (const float*)d_in[2];
    const float* Wo      = (const float*)d_in[3];
    const float* A_diag  = (const float*)d_in[4];
    const float* B_param = (const float*)d_in[5];
    const float* C_param = (const float*)d_in[6];
    const float* Dv      = (const float*)d_in[7];
    const float* dtp     = (const float*)d_in[8];
    const float* nw      = (const float*)d_in[9];
    float* out = (float*)d_out;

    char* ws = (char*)d_ws;
    ushort* hsb  = (ushort*)ws;                                   ws += (size_t)MT * HH * 2;   // 16 MB
    ushort* Wigb = (ushort*)ws;                                   ws += (size_t)C2 * HH * 2;   //  4 MB
    ushort* Wob  = (ushort*)ws;                                   ws += (size_t)HH * HH * 2;   //  2 MB
    ushort* Bpkb = (ushort*)ws;                                   ws += (size_t)C2 * HH * 2;   //  4 MB
    ushort* Cpkb = (ushort*)ws;                                   ws += (size_t)HH * C2 * 2;   //  4 MB
    ushort* XGb  = (ushort*)ws;                                   ws += (size_t)MT * C2 * 2;   // 32 MB
    ushort* Bu   = (ushort*)ws;                                   ws += (size_t)MT * C2 * 2;   // 32 MB
    ushort* YSb  = (ushort*)ws;                                   ws += (size_t)MT * C2 * 2;   // 32 MB
    ushort* O    = (ushort*)ws;                                   ws += (size_t)MT * HH * 2;   // 16 MB
    ushort* Vb   = (ushort*)ws;                                   ws += (size_t)MT * HH * 2;   // 16 MB
    float2* sEnd  = (float2*)ws;                                  ws += (size_t)NC * BB * C2 * 8;
    float2* sInit = (float2*)ws;

    dim3 blk(256);

    // single fused prep kernel (converts + repacks)
    prep_all<<<dim3(PREP_TOT / 256), blk, 0, stream>>>(
        hs, Wi, Wg, Wo, B_param, C_param, hsb, Wigb, Wob, Bpkb, Cpkb);

    // A/B EXPERIMENT (same shape M=8192,N=2048,K=1024):
    // XG (treatment): gemm2b, 1024 blocks, 2 blk/CU
    gemm2b<1><<<dim3(1024), dim3(256), 0, stream>>>(
        hsb, HH, Wigb, HH, XGb, C2, HH, 16);

    // Bu (control): gemm8p 256x256, unchanged
    gemm8p<256, 1><<<dim3(256), dim3(512), 0, stream>>>(
        XGb, C2, Bpkb, HH, Bu, C2, HH, 8);

    // chunked linear scan (fp32 state over bf16 Bu), YS emitted as bf16
    scan_passA<<<dim3(C2 / 256, BB, NC), blk, 0, stream>>>(Bu, A_diag, dtp, sEnd);
    scan_combine<<<dim3((BB * C2) / 256), blk, 0, stream>>>(A_diag, dtp, sEnd, sInit);
    scan_passB<<<dim3(C2 / 256, BB, NC), blk, 0, stream>>>(Bu, A_diag, dtp, sInit, YSb);

    // O = YS @ Cpk^T        (M=8192, N=1024, K=2048) -> bf16 (2-blocks/CU)
    gemm2b<1><<<dim3(512), dim3(256), 0, stream>>>(
        YSb, C2, Cpkb, C2, O, HH, C2, 8);

    // fused D*x + RMSNorm + swish gate -> V (bf16)
    rmsgate_kernel<<<dim3(MT), blk, 0, stream>>>(O, XGb, Dv, nw, Vb);

    // out = V @ Wo^T        (M=8192, N=1024, K=1024) -> fp32 (2-blocks/CU)
    gemm2b<0><<<dim3(512), dim3(256), 0, stream>>>(
        Vb, HH, Wob, HH, out, HH, HH, 8);
}